// Round 1
// 900.600 us; speedup vs baseline: 1.4751x; 1.4751x over previous
//
#include <hip/hip_runtime.h>
#include <hip/hip_bf16.h>

#define BB 4
#define SS 1024
#define HID 1024
#define NH 16
#define NKV 4
#define DH 64
#define NREP 4

typedef __hip_bfloat16 bf16;
typedef __attribute__((ext_vector_type(8))) short bf16x8;   // 8 bf16 (4 VGPRs)
typedef __attribute__((ext_vector_type(4))) short short4v;  // 4 bf16 (8 B)
typedef __attribute__((ext_vector_type(4))) float f32x4;
typedef __attribute__((ext_vector_type(4))) unsigned int uint4v;

__device__ inline float toF(float x) { return x; }
__device__ inline float toF(bf16 x) { return __bfloat162float(x); }
__device__ inline short f2bf(float x) {
  bf16 h = __float2bfloat16(x);
  return *reinterpret_cast<short*>(&h);
}

// ---------------------------------------------------------------------------
// Tiled vector GEMM: C[M,N] = A[M,K] @ Bw[K,N], fp32 accumulate.
// MODE 0: bf16 row-major [M][N]
// MODE 1: bf16 KV layout  [B][NKV][S][DH]   (r=(b,s), c=(kvh,dh))
// MODE 2: bf16 V^T layout [B][NKV][DH][S]
// MODE 3: fp32 row-major [M][N]
// ---------------------------------------------------------------------------
template <typename AT, int MODE>
__global__ __launch_bounds__(256) void gemm_tiled(const AT* __restrict__ A,
                                                  const float* __restrict__ Bw,
                                                  void* __restrict__ Cv,
                                                  int M, int N, int K) {
  __shared__ float As[64][17];
  __shared__ float Bs[16][64];
  const int t = threadIdx.x;
  const int tx = t & 15;
  const int ty = t >> 4;
  const int rowBase = blockIdx.y * 64;
  const int colBase = blockIdx.x * 64;

  float acc[4][4] = {};

  for (int k0 = 0; k0 < K; k0 += 16) {
#pragma unroll
    for (int i = 0; i < 4; i++) {
      int idx = t + i * 256;  // 0..1023
      int m = idx >> 4;
      int kk = idx & 15;
      As[m][kk] = toF(A[(size_t)(rowBase + m) * K + k0 + kk]);
    }
#pragma unroll
    for (int i = 0; i < 4; i++) {
      int idx = t + i * 256;
      int kk = idx >> 6;
      int n = idx & 63;
      Bs[kk][n] = Bw[(size_t)(k0 + kk) * N + colBase + n];
    }
    __syncthreads();

#pragma unroll
    for (int kk = 0; kk < 16; kk++) {
      float a[4], b[4];
#pragma unroll
      for (int i = 0; i < 4; i++) a[i] = As[ty * 4 + i][kk];
#pragma unroll
      for (int j = 0; j < 4; j++) b[j] = Bs[kk][tx * 4 + j];
#pragma unroll
      for (int i = 0; i < 4; i++)
#pragma unroll
        for (int j = 0; j < 4; j++) acc[i][j] += a[i] * b[j];
    }
    __syncthreads();
  }

#pragma unroll
  for (int i = 0; i < 4; i++) {
#pragma unroll
    for (int j = 0; j < 4; j++) {
      int r = rowBase + ty * 4 + i;
      int c = colBase + tx * 4 + j;
      float val = acc[i][j];
      if (MODE == 3) {
        ((float*)Cv)[(size_t)r * N + c] = val;
      } else if (MODE == 0) {
        ((short*)Cv)[(size_t)r * N + c] = f2bf(val);
      } else {
        int bb = r >> 10, s = r & (SS - 1);
        int kvh = c >> 6, dh = c & (DH - 1);
        size_t off = (MODE == 1)
                         ? ((((size_t)bb * NKV + kvh) * SS + s) * DH + dh)
                         : ((((size_t)bb * NKV + kvh) * DH + dh) * SS + s);
        ((short*)Cv)[off] = f2bf(val);
      }
    }
  }
}

// ---------------------------------------------------------------------------
// MFMA flash attention.
// Block = (16 q-rows, kvh, b); 4 waves = 4 rep heads sharing K/V.
// K staged [64 key][64 dh], V^T staged [64 dh][64 key], both XOR-swizzled:
//   lds_byte(row, colbyte) = row*128 + (colbyte ^ ((row&7)<<4))
// mfma_f32_16x16x32_bf16 C-layout: col = lane&15, row = (lane>>4)*4 + reg.
// A-frag: m = lane&15, k-pattern shared by A/B loads (permutation-invariant).
// ---------------------------------------------------------------------------
__global__ __launch_bounds__(256) void attn_mfma(
    const bf16* __restrict__ qm,    // [B,S,NH*DH]
    const bf16* __restrict__ km,    // [B,NKV,S,DH]
    const bf16* __restrict__ vtm,   // [B,NKV,DH,S]
    const float* __restrict__ bias, // [B,NH,S,S]
    const int* __restrict__ mask,   // [B,1,S,S]
    bf16* __restrict__ attn)        // [B,S,NH*DH]
{
  const int qt = blockIdx.x;
  const int kvh = blockIdx.y;
  const int b = blockIdx.z;
  const int q0 = qt * 16;

  __shared__ short kls[64 * 64];      // 8 KB
  __shared__ short vls[64 * 64];      // 8 KB
  __shared__ short pls[4][16 * 68];   // 8.5 KB (row pad 8B -> conflict-free)

  const int t = threadIdx.x;
  const int wv = t >> 6;
  const int lane = t & 63;
  const int lrow = lane & 15;
  const int lhi = lane >> 4;
  const int h = kvh * NREP + wv;

  // ---- Q fragments, held in registers for the whole kernel ----
  const short* qg =
      (const short*)qm + (size_t)(b * SS + q0 + lrow) * (NH * DH) + h * DH;
  bf16x8 qf[2];
#pragma unroll
  for (int ks = 0; ks < 2; ks++) {
    ((short4v*)&qf[ks])[0] = *(const short4v*)(qg + ks * 32 + lhi * 4);
    ((short4v*)&qf[ks])[1] = *(const short4v*)(qg + ks * 32 + 16 + lhi * 4);
  }

  float mrow[4], lsum[4];
  f32x4 oacc[4];
#pragma unroll
  for (int i = 0; i < 4; i++) {
    mrow[i] = -3e38f;
    lsum[i] = 0.f;
    oacc[i] = (f32x4){0.f, 0.f, 0.f, 0.f};
  }

  const short* kg = (const short*)km + (size_t)(b * NKV + kvh) * SS * DH;
  const short* vg = (const short*)vtm + (size_t)(b * NKV + kvh) * DH * SS;
  const float* bb_ = bias + ((size_t)(b * NH + h) * SS + q0) * SS;
  const int* mb_ = mask + ((size_t)(b * SS) + q0) * SS;

  for (int k0 = 0; k0 < SS; k0 += 64) {
    __syncthreads();
    // ---- stage K tile and V^T tile (reg-staged, swizzled) ----
#pragma unroll
    for (int i = 0; i < 2; i++) {
      int idx = t + i * 256;       // 512 chunks of 16B per tile
      int row = idx >> 3;
      int c16 = idx & 7;
      int soff = row * 64 + ((((c16 << 4) ^ ((row & 7) << 4))) >> 1);
      *(uint4v*)(kls + soff) =
          *(const uint4v*)(kg + (size_t)(k0 + row) * DH + c16 * 8);
      *(uint4v*)(vls + soff) =
          *(const uint4v*)(vg + (size_t)row * SS + k0 + c16 * 8);
    }
    __syncthreads();

    // ---- QK^T: 4 n-blocks x 2 k-steps of 32 over dh ----
    f32x4 sacc[4];
#pragma unroll
    for (int nb = 0; nb < 4; nb++) sacc[nb] = (f32x4){0.f, 0.f, 0.f, 0.f};
#pragma unroll
    for (int nb = 0; nb < 4; nb++) {
      int krow = nb * 16 + lrow;
      const char* kb = (const char*)(kls + krow * 64);
      int sw = (krow & 7) << 4;
#pragma unroll
      for (int ks = 0; ks < 2; ks++) {
        int c0 = ks * 64 + lhi * 8;
        bf16x8 kf;
        ((short4v*)&kf)[0] = *(const short4v*)(kb + (c0 ^ sw));
        ((short4v*)&kf)[1] = *(const short4v*)(kb + ((c0 + 32) ^ sw));
        sacc[nb] =
            __builtin_amdgcn_mfma_f32_16x16x32_bf16(qf[ks], kf, sacc[nb], 0, 0, 0);
      }
    }

    // ---- bias + mask + online softmax (row across lanes l&15) ----
    float p[4][4];
#pragma unroll
    for (int ri = 0; ri < 4; ri++) {
      int row = lhi * 4 + ri;
      const float* br = bb_ + (size_t)row * SS + k0 + lrow;
      const int* mr = mb_ + (size_t)row * SS + k0 + lrow;
      float tm = -3e38f;
#pragma unroll
      for (int nb = 0; nb < 4; nb++) {
        float s = sacc[nb][ri] * 0.125f + br[nb * 16];
        s = (mr[nb * 16] != 0) ? s : -1e9f;
        p[ri][nb] = s;
        tm = fmaxf(tm, s);
      }
#pragma unroll
      for (int off = 8; off; off >>= 1) tm = fmaxf(tm, __shfl_xor(tm, off));
      float mnew = fmaxf(mrow[ri], tm);
      float scale = __expf(mrow[ri] - mnew);
      mrow[ri] = mnew;
      float rs = 0.f;
#pragma unroll
      for (int nb = 0; nb < 4; nb++) {
        float e = __expf(p[ri][nb] - mnew);
        p[ri][nb] = e;
        rs += e;
      }
#pragma unroll
      for (int off = 8; off; off >>= 1) rs += __shfl_xor(rs, off);
      lsum[ri] = lsum[ri] * scale + rs;
#pragma unroll
      for (int nb = 0; nb < 4; nb++) oacc[nb][ri] *= scale;
    }

    // ---- P (C-layout) -> LDS -> A-fragment layout ----
    short* pw = pls[wv];
#pragma unroll
    for (int ri = 0; ri < 4; ri++) {
      int row = lhi * 4 + ri;
#pragma unroll
      for (int nb = 0; nb < 4; nb++)
        pw[row * 68 + nb * 16 + lrow] = f2bf(p[ri][nb]);
    }
    __builtin_amdgcn_wave_barrier();  // same-wave LDS RAW; block reordering
    const short* pr = pls[wv] + lrow * 68;
    bf16x8 pf[2];
#pragma unroll
    for (int ks = 0; ks < 2; ks++) {
      ((short4v*)&pf[ks])[0] = *(const short4v*)(pr + ks * 32 + lhi * 4);
      ((short4v*)&pf[ks])[1] = *(const short4v*)(pr + ks * 32 + 16 + lhi * 4);
    }

    // ---- PV: O[16 x 64dh] += P[16 x 64key] @ V[64key x 64dh] ----
#pragma unroll
    for (int nd = 0; nd < 4; nd++) {
      int vrow = nd * 16 + lrow;   // dh row of V^T tile
      const char* vb = (const char*)(vls + vrow * 64);
      int sw = (vrow & 7) << 4;
#pragma unroll
      for (int ks = 0; ks < 2; ks++) {
        int c0 = ks * 64 + lhi * 8;
        bf16x8 vf;
        ((short4v*)&vf)[0] = *(const short4v*)(vb + (c0 ^ sw));
        ((short4v*)&vf)[1] = *(const short4v*)(vb + ((c0 + 32) ^ sw));
        oacc[nd] =
            __builtin_amdgcn_mfma_f32_16x16x32_bf16(pf[ks], vf, oacc[nd], 0, 0, 0);
      }
    }
  }

  // ---- epilogue: normalize and store ----
  short* og = (short*)attn + (size_t)(b * SS + q0) * (NH * DH) + h * DH;
#pragma unroll
  for (int ri = 0; ri < 4; ri++) {
    float inv = 1.0f / lsum[ri];
    int row = lhi * 4 + ri;
#pragma unroll
    for (int nd = 0; nd < 4; nd++)
      og[(size_t)row * (NH * DH) + nd * 16 + lrow] = f2bf(oacc[nd][ri] * inv);
  }
}

// ---------------------------------------------------------------------------
extern "C" void kernel_launch(void* const* d_in, const int* in_sizes, int n_in,
                              void* d_out, int out_size, void* d_ws,
                              size_t ws_size, hipStream_t stream) {
  const float* hs = (const float*)d_in[0];    // [B,S,HID]      fp32
  const float* bias = (const float*)d_in[1];  // [B,NH,S,S]     fp32
  const int* mask = (const int*)d_in[2];      // [B,1,S,S]      int32
  const float* Wq = (const float*)d_in[3];    // [HID, NH*DH]   fp32
  const float* Wk = (const float*)d_in[4];    // [HID, NKV*DH]  fp32
  const float* Wv = (const float*)d_in[5];    // [HID, NKV*DH]  fp32
  const float* Wo = (const float*)d_in[6];    // [HID, HID]     fp32
  float* out = (float*)d_out;                 // [B,S,HID]      fp32

  bf16* q = (bf16*)d_ws;                      // [B,S,NH*DH]    8 MB
  bf16* k = q + (size_t)BB * SS * NH * DH;    // [B,NKV,S,DH]   2 MB
  bf16* v = k + (size_t)BB * SS * NKV * DH;   // [B,NKV,DH,S]   2 MB
  bf16* at = v + (size_t)BB * SS * NKV * DH;  // [B,S,NH*DH]    8 MB

  const int M = BB * SS;  // 4096

  gemm_tiled<float, 0>
      <<<dim3(NH * DH / 64, M / 64), 256, 0, stream>>>(hs, Wq, q, M, NH * DH, HID);
  gemm_tiled<float, 1>
      <<<dim3(NKV * DH / 64, M / 64), 256, 0, stream>>>(hs, Wk, k, M, NKV * DH, HID);
  gemm_tiled<float, 2>
      <<<dim3(NKV * DH / 64, M / 64), 256, 0, stream>>>(hs, Wv, v, M, NKV * DH, HID);

  attn_mfma<<<dim3(SS / 16, NKV, BB), 256, 0, stream>>>(q, k, v, bias, mask, at);

  gemm_tiled<bf16, 3>
      <<<dim3(HID / 64, M / 64), 256, 0, stream>>>(at, Wo, out, M, HID, HID);
}

// Round 3
// 664.374 us; speedup vs baseline: 1.9996x; 1.3556x over previous
//
#include <hip/hip_runtime.h>
#include <hip/hip_bf16.h>
#include <type_traits>

#define BB 4
#define SS 1024
#define HID 1024
#define NH 16
#define NKV 4
#define DH 64
#define NREP 4

typedef __hip_bfloat16 bf16;
typedef __attribute__((ext_vector_type(8))) short bf16x8;   // 8 bf16 (4 VGPRs)
typedef __attribute__((ext_vector_type(4))) short short4v;  // 4 bf16 (8 B)
typedef __attribute__((ext_vector_type(4))) float f32x4;
typedef __attribute__((ext_vector_type(4))) unsigned int uint4v;

__device__ inline short f2bf(float x) {
  bf16 h = __float2bfloat16(x);
  return *reinterpret_cast<short*>(&h);
}
__device__ inline float bf2f(short x) {
  bf16 h = *reinterpret_cast<bf16*>(&x);
  return __bfloat162float(h);
}
// fp32 -> bf16 hi/lo pair: x ~= hi + lo with ~16 mantissa bits.
struct BfPair {
  short hi, lo;
};
__device__ inline BfPair split2(float x) {
  BfPair r;
  r.hi = f2bf(x);
  r.lo = f2bf(x - bf2f(r.hi));
  return r;
}

// Fragment read from a [row][36-short-padded] LDS plane. Lane's 8 k-slots are
// shorts lhi*8..+7 of the row — identical pattern for A and B operands, so any
// internal MFMA k-slot mapping yields the correct dot product.
__device__ inline bf16x8 frag_read(const short* plane, int row, int lhi) {
  const short* p = plane + row * 36 + lhi * 8;
  bf16x8 f;
  ((short4v*)&f)[0] = *(const short4v*)(p);
  ((short4v*)&f)[1] = *(const short4v*)(p + 4);
  return f;
}

// ---------------------------------------------------------------------------
// Split-bf16 MFMA GEMM: C[M,N] = A[M,K] @ Bw[K,N] with fp32-class accuracy.
//   A fp32  -> split into (Ah, Al): acc = Ah*Bh + Ah*Bl + Al*Bh  (3 passes)
//   A bf16  -> exact:               acc = A*Bh  + A*Bl           (2 passes)
// Tile: BM x 64, BK=32, 4 waves (2x2), each wave 32x32 (MI x 2 fragments).
// LDS planes [row][k] with 72B-padded rows (conflict-free frag reads).
// MODE 0:  C bf16 [M][N]                    (q projection)
// MODE 3:  C fp32 [M][N]                    (final out)
// MODE 12: dual KV launch, blockIdx.z: z=0 -> B0/C0 K-layout [B][NKV][S][DH]
//                                     z=1 -> B1/C1 V^T      [B][NKV][DH][S]
// ---------------------------------------------------------------------------
template <typename AT, int BM, int MODE>
__global__ __launch_bounds__(256) void gemm_mfma(
    const AT* __restrict__ A, const float* __restrict__ B0,
    const float* __restrict__ B1, void* __restrict__ C0, void* __restrict__ C1,
    int M, int N, int K) {
  constexpr bool SPLIT_A = std::is_same<AT, float>::value;
  constexpr int APL = SPLIT_A ? 2 : 1;
  constexpr int MI = BM / 32;  // fragments per wave in M
  __shared__ __align__(16) short lds[(BM * APL + 128) * 36];
  short* Ah = lds;
  short* Al = lds + (SPLIT_A ? BM * 36 : 0);  // aliases Ah when unused
  short* Bh = lds + BM * APL * 36;
  short* Bl = Bh + 64 * 36;

  const int t = threadIdx.x;
  const int wv = t >> 6;
  const int lane = t & 63;
  const int lrow = lane & 15;
  const int lhi = lane >> 4;
  const int wr = wv >> 1;  // 0..1
  const int wc = wv & 1;   // 0..1
  const int rowBase = blockIdx.y * BM;
  const int colBase = blockIdx.x * 64;
  const float* Bw = B0;
  if (MODE == 12 && blockIdx.z) Bw = B1;

  f32x4 acc[MI][2];
#pragma unroll
  for (int mi = 0; mi < MI; mi++)
#pragma unroll
    for (int ni = 0; ni < 2; ni++) acc[mi][ni] = (f32x4){0.f, 0.f, 0.f, 0.f};

  for (int k0 = 0; k0 < K; k0 += 32) {
    __syncthreads();  // previous iter's frag reads done before overwrite
    // ---- stage A tile [BM][32] ----
    if constexpr (SPLIT_A) {
#pragma unroll
      for (int i = 0; i < BM / 32; i++) {
        int idx = t + i * 256;
        int r = idx >> 3;
        int c4 = (idx & 7) * 4;
        float4 v = *(const float4*)&A[(size_t)(rowBase + r) * K + k0 + c4];
        short4v h, l;
        BfPair p0 = split2(v.x), p1 = split2(v.y), p2 = split2(v.z),
               p3 = split2(v.w);
        h[0] = p0.hi; l[0] = p0.lo;
        h[1] = p1.hi; l[1] = p1.lo;
        h[2] = p2.hi; l[2] = p2.lo;
        h[3] = p3.hi; l[3] = p3.lo;
        *(short4v*)(Ah + r * 36 + c4) = h;
        *(short4v*)(Al + r * 36 + c4) = l;
      }
    } else {
#pragma unroll
      for (int i = 0; i < BM / 64; i++) {
        int idx = t + i * 256;
        int r = idx >> 2;
        int c8 = (idx & 3) * 8;
        uint4v v =
            *(const uint4v*)((const short*)A + (size_t)(rowBase + r) * K + k0 + c8);
        *(short4v*)(Ah + r * 36 + c8) = ((short4v*)&v)[0];
        *(short4v*)(Ah + r * 36 + c8 + 4) = ((short4v*)&v)[1];
      }
    }
    // ---- stage B tile transposed: Bs[n][k], n in [0,64), k in [0,32) ----
#pragma unroll
    for (int i = 0; i < 2; i++) {
      int idx = t + i * 256;
      int n = idx & 63;
      int k4 = (idx >> 6) * 4;
      short4v h, l;
#pragma unroll
      for (int j = 0; j < 4; j++) {
        float x = Bw[(size_t)(k0 + k4 + j) * N + colBase + n];
        BfPair pp = split2(x);
        h[j] = pp.hi;
        l[j] = pp.lo;
      }
      *(short4v*)(Bh + n * 36 + k4) = h;
      *(short4v*)(Bl + n * 36 + k4) = l;
    }
    __syncthreads();

    // ---- MFMA passes ----
    bf16x8 ah[MI], al[MI];
#pragma unroll
    for (int mi = 0; mi < MI; mi++) {
      int arow = wr * (BM / 2) + mi * 16 + lrow;
      ah[mi] = frag_read(Ah, arow, lhi);
      if constexpr (SPLIT_A) al[mi] = frag_read(Al, arow, lhi);
    }
#pragma unroll
    for (int ni = 0; ni < 2; ni++) {
      int brow = wc * 32 + ni * 16 + lrow;
      bf16x8 bh = frag_read(Bh, brow, lhi);
      bf16x8 bl = frag_read(Bl, brow, lhi);
#pragma unroll
      for (int mi = 0; mi < MI; mi++)
        acc[mi][ni] =
            __builtin_amdgcn_mfma_f32_16x16x32_bf16(ah[mi], bh, acc[mi][ni], 0, 0, 0);
#pragma unroll
      for (int mi = 0; mi < MI; mi++)
        acc[mi][ni] =
            __builtin_amdgcn_mfma_f32_16x16x32_bf16(ah[mi], bl, acc[mi][ni], 0, 0, 0);
      if constexpr (SPLIT_A) {
#pragma unroll
        for (int mi = 0; mi < MI; mi++)
          acc[mi][ni] = __builtin_amdgcn_mfma_f32_16x16x32_bf16(al[mi], bh,
                                                                acc[mi][ni], 0, 0, 0);
      }
    }
  }

  // ---- epilogue: C-layout col = lane&15, row = (lane>>4)*4 + reg ----
#pragma unroll
  for (int mi = 0; mi < MI; mi++) {
#pragma unroll
    for (int ni = 0; ni < 2; ni++) {
#pragma unroll
      for (int j = 0; j < 4; j++) {
        int r = rowBase + wr * (BM / 2) + mi * 16 + lhi * 4 + j;
        int c = colBase + wc * 32 + ni * 16 + lrow;
        float val = acc[mi][ni][j];
        if constexpr (MODE == 0) {
          ((short*)C0)[(size_t)r * N + c] = f2bf(val);
        } else if constexpr (MODE == 3) {
          ((float*)C0)[(size_t)r * N + c] = val;
        } else {
          int bb = r >> 10, s = r & (SS - 1);
          int kvh = c >> 6, dh = c & (DH - 1);
          if (blockIdx.z == 0)
            ((short*)C0)[(((size_t)bb * NKV + kvh) * SS + s) * DH + dh] = f2bf(val);
          else
            ((short*)C1)[(((size_t)bb * NKV + kvh) * DH + dh) * SS + s] = f2bf(val);
        }
      }
    }
  }
}

// ---------------------------------------------------------------------------
// MFMA flash attention (unchanged).
// ---------------------------------------------------------------------------
__global__ __launch_bounds__(256) void attn_mfma(
    const bf16* __restrict__ qm,    // [B,S,NH*DH]
    const bf16* __restrict__ km,    // [B,NKV,S,DH]
    const bf16* __restrict__ vtm,   // [B,NKV,DH,S]
    const float* __restrict__ bias, // [B,NH,S,S]
    const int* __restrict__ mask,   // [B,1,S,S]
    bf16* __restrict__ attn)        // [B,S,NH*DH]
{
  const int qt = blockIdx.x;
  const int kvh = blockIdx.y;
  const int b = blockIdx.z;
  const int q0 = qt * 16;

  __shared__ short kls[64 * 64];      // 8 KB
  __shared__ short vls[64 * 64];      // 8 KB
  __shared__ short pls[4][16 * 68];   // 8.5 KB

  const int t = threadIdx.x;
  const int wv = t >> 6;
  const int lane = t & 63;
  const int lrow = lane & 15;
  const int lhi = lane >> 4;
  const int h = kvh * NREP + wv;

  const short* qg =
      (const short*)qm + (size_t)(b * SS + q0 + lrow) * (NH * DH) + h * DH;
  bf16x8 qf[2];
#pragma unroll
  for (int ks = 0; ks < 2; ks++) {
    ((short4v*)&qf[ks])[0] = *(const short4v*)(qg + ks * 32 + lhi * 4);
    ((short4v*)&qf[ks])[1] = *(const short4v*)(qg + ks * 32 + 16 + lhi * 4);
  }

  float mrow[4], lsum[4];
  f32x4 oacc[4];
#pragma unroll
  for (int i = 0; i < 4; i++) {
    mrow[i] = -3e38f;
    lsum[i] = 0.f;
    oacc[i] = (f32x4){0.f, 0.f, 0.f, 0.f};
  }

  const short* kg = (const short*)km + (size_t)(b * NKV + kvh) * SS * DH;
  const short* vg = (const short*)vtm + (size_t)(b * NKV + kvh) * DH * SS;
  const float* bb_ = bias + ((size_t)(b * NH + h) * SS + q0) * SS;
  const int* mb_ = mask + ((size_t)(b * SS) + q0) * SS;

  for (int k0 = 0; k0 < SS; k0 += 64) {
    __syncthreads();
#pragma unroll
    for (int i = 0; i < 2; i++) {
      int idx = t + i * 256;
      int row = idx >> 3;
      int c16 = idx & 7;
      int soff = row * 64 + ((((c16 << 4) ^ ((row & 7) << 4))) >> 1);
      *(uint4v*)(kls + soff) =
          *(const uint4v*)(kg + (size_t)(k0 + row) * DH + c16 * 8);
      *(uint4v*)(vls + soff) =
          *(const uint4v*)(vg + (size_t)row * SS + k0 + c16 * 8);
    }
    __syncthreads();

    f32x4 sacc[4];
#pragma unroll
    for (int nb = 0; nb < 4; nb++) sacc[nb] = (f32x4){0.f, 0.f, 0.f, 0.f};
#pragma unroll
    for (int nb = 0; nb < 4; nb++) {
      int krow = nb * 16 + lrow;
      const char* kb = (const char*)(kls + krow * 64);
      int sw = (krow & 7) << 4;
#pragma unroll
      for (int ks = 0; ks < 2; ks++) {
        int c0 = ks * 64 + lhi * 8;
        bf16x8 kf;
        ((short4v*)&kf)[0] = *(const short4v*)(kb + (c0 ^ sw));
        ((short4v*)&kf)[1] = *(const short4v*)(kb + ((c0 + 32) ^ sw));
        sacc[nb] =
            __builtin_amdgcn_mfma_f32_16x16x32_bf16(qf[ks], kf, sacc[nb], 0, 0, 0);
      }
    }

    float p[4][4];
#pragma unroll
    for (int ri = 0; ri < 4; ri++) {
      int row = lhi * 4 + ri;
      const float* br = bb_ + (size_t)row * SS + k0 + lrow;
      const int* mr = mb_ + (size_t)row * SS + k0 + lrow;
      float tm = -3e38f;
#pragma unroll
      for (int nb = 0; nb < 4; nb++) {
        float s = sacc[nb][ri] * 0.125f + br[nb * 16];
        s = (mr[nb * 16] != 0) ? s : -1e9f;
        p[ri][nb] = s;
        tm = fmaxf(tm, s);
      }
#pragma unroll
      for (int off = 8; off; off >>= 1) tm = fmaxf(tm, __shfl_xor(tm, off));
      float mnew = fmaxf(mrow[ri], tm);
      float scale = __expf(mrow[ri] - mnew);
      mrow[ri] = mnew;
      float rs = 0.f;
#pragma unroll
      for (int nb = 0; nb < 4; nb++) {
        float e = __expf(p[ri][nb] - mnew);
        p[ri][nb] = e;
        rs += e;
      }
#pragma unroll
      for (int off = 8; off; off >>= 1) rs += __shfl_xor(rs, off);
      lsum[ri] = lsum[ri] * scale + rs;
#pragma unroll
      for (int nb = 0; nb < 4; nb++) oacc[nb][ri] *= scale;
    }

    short* pw = pls[wv];
#pragma unroll
    for (int ri = 0; ri < 4; ri++) {
      int row = lhi * 4 + ri;
#pragma unroll
      for (int nb = 0; nb < 4; nb++)
        pw[row * 68 + nb * 16 + lrow] = f2bf(p[ri][nb]);
    }
    __builtin_amdgcn_wave_barrier();
    const short* pr = pls[wv] + lrow * 68;
    bf16x8 pf[2];
#pragma unroll
    for (int ks = 0; ks < 2; ks++) {
      ((short4v*)&pf[ks])[0] = *(const short4v*)(pr + ks * 32 + lhi * 4);
      ((short4v*)&pf[ks])[1] = *(const short4v*)(pr + ks * 32 + 16 + lhi * 4);
    }

#pragma unroll
    for (int nd = 0; nd < 4; nd++) {
      int vrow = nd * 16 + lrow;
      const char* vb = (const char*)(vls + vrow * 64);
      int sw = (vrow & 7) << 4;
#pragma unroll
      for (int ks = 0; ks < 2; ks++) {
        int c0 = ks * 64 + lhi * 8;
        bf16x8 vf;
        ((short4v*)&vf)[0] = *(const short4v*)(vb + (c0 ^ sw));
        ((short4v*)&vf)[1] = *(const short4v*)(vb + ((c0 + 32) ^ sw));
        oacc[nd] =
            __builtin_amdgcn_mfma_f32_16x16x32_bf16(pf[ks], vf, oacc[nd], 0, 0, 0);
      }
    }
  }

  short* og = (short*)attn + (size_t)(b * SS + q0) * (NH * DH) + h * DH;
#pragma unroll
  for (int ri = 0; ri < 4; ri++) {
    float inv = 1.0f / lsum[ri];
    int row = lhi * 4 + ri;
#pragma unroll
    for (int nd = 0; nd < 4; nd++)
      og[(size_t)row * (NH * DH) + nd * 16 + lrow] = f2bf(oacc[nd][ri] * inv);
  }
}

// ---------------------------------------------------------------------------
extern "C" void kernel_launch(void* const* d_in, const int* in_sizes, int n_in,
                              void* d_out, int out_size, void* d_ws,
                              size_t ws_size, hipStream_t stream) {
  const float* hs = (const float*)d_in[0];    // [B,S,HID]      fp32
  const float* bias = (const float*)d_in[1];  // [B,NH,S,S]     fp32
  const int* mask = (const int*)d_in[2];      // [B,1,S,S]      int32
  const float* Wq = (const float*)d_in[3];    // [HID, NH*DH]   fp32
  const float* Wk = (const float*)d_in[4];    // [HID, NKV*DH]  fp32
  const float* Wv = (const float*)d_in[5];    // [HID, NKV*DH]  fp32
  const float* Wo = (const float*)d_in[6];    // [HID, HID]     fp32
  float* out = (float*)d_out;                 // [B,S,HID]      fp32

  bf16* q = (bf16*)d_ws;                      // [B,S,NH*DH]    8 MB
  bf16* k = q + (size_t)BB * SS * NH * DH;    // [B,NKV,S,DH]   2 MB
  bf16* v = k + (size_t)BB * SS * NKV * DH;   // [B,NKV,DH,S]   2 MB
  bf16* at = v + (size_t)BB * SS * NKV * DH;  // [B,S,NH*DH]    8 MB

  const int M = BB * SS;  // 4096

  gemm_mfma<float, 64, 0><<<dim3(NH * DH / 64, M / 64), 256, 0, stream>>>(
      hs, Wq, nullptr, q, nullptr, M, NH * DH, HID);
  gemm_mfma<float, 64, 12><<<dim3(NKV * DH / 64, M / 64, 2), 256, 0, stream>>>(
      hs, Wk, Wv, k, v, M, NKV * DH, HID);

  attn_mfma<<<dim3(SS / 16, NKV, BB), 256, 0, stream>>>(q, k, v, bias, mask, at);

  gemm_mfma<bf16, 64, 3><<<dim3(HID / 64, M / 64), 256, 0, stream>>>(
      at, Wo, nullptr, out, nullptr, M, HID, HID);
}